// Round 1
// baseline (1901.842 us; speedup 1.0000x reference)
//
#include <hip/hip_runtime.h>
#include <math.h>

#define NNODES 100000
#define NGRAPHS 64

// ---------------- degree / norm ----------------

__global__ void deg_init(float* deg, int n) {
    int i = blockIdx.x * blockDim.x + threadIdx.x;
    if (i < n) deg[i] = 1.0f;  // self-loop contribution
}

__global__ void deg_edges(const int* dst, float* deg, int E) {
    int e = blockIdx.x * blockDim.x + threadIdx.x;
    if (e < E) atomicAdd(&deg[dst[e]], 1.0f);
}

__global__ void make_dinv(float* deg, int n) {
    int i = blockIdx.x * blockDim.x + threadIdx.x;
    if (i < n) {
        float d = deg[i];
        deg[i] = d > 0.0f ? rsqrtf(d) : 0.0f;  // in-place: deg becomes dinv
    }
}

// ---------------- dense matmul  out[n,COUT] = x[n,K] @ W[K,COUT] ----------------

template <int K, int COUT>
__global__ void mm_kernel(const float* __restrict__ x, const float* __restrict__ W,
                          float* __restrict__ out, int n) {
    int t = blockIdx.x * blockDim.x + threadIdx.x;
    if (t >= n * COUT) return;
    int i = t / COUT;
    int f = t - i * COUT;
    float acc = 0.0f;
#pragma unroll
    for (int k = 0; k < K; ++k) acc += x[i * K + k] * W[k * COUT + f];
    out[t] = acc;
}

// ---------------- scatter: self-loop init (write) + edge accumulate (atomic) ----------------

template <int C>
__global__ void scat_self(const float* __restrict__ h, const float* __restrict__ dinv,
                          float* __restrict__ out, int n) {
    int t = blockIdx.x * blockDim.x + threadIdx.x;
    if (t >= n * C) return;
    int i = t / C;
    float di = dinv[i];
    out[t] = h[t] * di * di;
}

template <int C>
__global__ void scat_edge(const int* __restrict__ src, const int* __restrict__ dst,
                          const float* __restrict__ h, const float* __restrict__ dinv,
                          float* __restrict__ out, int E) {
    int t = blockIdx.x * blockDim.x + threadIdx.x;
    if (t >= E * C) return;
    int e = t / C;
    int f = t - e * C;
    int s = src[e];
    int d = dst[e];
    float nrm = dinv[s] * dinv[d];
    atomicAdd(&out[d * C + f], h[s * C + f] * nrm);
}

// ---------------- bias + relu (in place) ----------------

template <int C>
__global__ void bias_relu(float* __restrict__ x, const float* __restrict__ b, int n) {
    int t = blockIdx.x * blockDim.x + threadIdx.x;
    if (t >= n * C) return;
    int f = t % C;
    float v = x[t] + b[f];
    x[t] = v > 0.0f ? v : 0.0f;
}

// ---------------- pooling ----------------

__global__ void pool_accum(const float* __restrict__ y, const int* __restrict__ batch,
                           float* __restrict__ sums, float* __restrict__ cnt, int n) {
    int t = blockIdx.x * blockDim.x + threadIdx.x;
    if (t >= n * 24) return;
    int i = t / 24;
    int c = t - i * 24;
    int g = batch[i];
    atomicAdd(&sums[g * 24 + c], y[t]);
    if (c == 0) atomicAdd(&cnt[g], 1.0f);
}

__global__ void pool_finish(const float* __restrict__ sums, const float* __restrict__ cnt,
                            const float* __restrict__ b3, float* __restrict__ out) {
    int t = blockIdx.x * blockDim.x + threadIdx.x;
    if (t >= NGRAPHS * 24) return;
    int g = t / 24;
    int c = t - g * 24;
    float m = sums[t] / fmaxf(cnt[g], 1.0f) + b3[c];
    out[t] = tanhf(m);
}

// ---------------- launch ----------------

static inline int gridFor(long long total, int block) {
    return (int)((total + block - 1) / block);
}

extern "C" void kernel_launch(void* const* d_in, const int* in_sizes, int n_in,
                              void* d_out, int out_size, void* d_ws, size_t ws_size,
                              hipStream_t stream) {
    const float* pos   = (const float*)d_in[0];
    const int*   ei    = (const int*)d_in[1];
    const int*   batch = (const int*)d_in[2];
    const float* W1    = (const float*)d_in[3];
    const float* b1    = (const float*)d_in[4];
    const float* W2    = (const float*)d_in[5];
    const float* b2    = (const float*)d_in[6];
    const float* W3    = (const float*)d_in[7];
    const float* b3    = (const float*)d_in[8];
    float*       out   = (float*)d_out;

    const int N = NNODES;
    const int E = in_sizes[1] / 2;
    const int* src = ei;
    const int* dst = ei + E;

    // workspace layout (floats)
    float* ws   = (float*)d_ws;
    float* dinv = ws;                 // N     (deg -> dinv in place)
    float* bufH = dinv + N;           // N*64  (pre-aggregation features)
    float* bufA = bufH + (size_t)N * 64;  // N*64  (aggregated features)
    float* bufY = bufA + (size_t)N * 64;  // N*24  (layer-3 aggregate)
    float* pool = bufY + (size_t)N * 24;  // 64*24 sums
    float* cnt  = pool + NGRAPHS * 24;    // 64 counts

    const int B = 256;

    // --- norm ---
    deg_init<<<gridFor(N, B), B, 0, stream>>>(dinv, N);
    deg_edges<<<gridFor(E, B), B, 0, stream>>>(dst, dinv, E);
    make_dinv<<<gridFor(N, B), B, 0, stream>>>(dinv, N);

    // --- layer 1: pos[N,3] @ W1[3,64] ---
    mm_kernel<3, 64><<<gridFor((long long)N * 64, B), B, 0, stream>>>(pos, W1, bufH, N);
    scat_self<64><<<gridFor((long long)N * 64, B), B, 0, stream>>>(bufH, dinv, bufA, N);
    scat_edge<64><<<gridFor((long long)E * 64, B), B, 0, stream>>>(src, dst, bufH, dinv, bufA, E);
    bias_relu<64><<<gridFor((long long)N * 64, B), B, 0, stream>>>(bufA, b1, N);

    // --- layer 2: bufA[N,64] @ W2[64,64] ---
    mm_kernel<64, 64><<<gridFor((long long)N * 64, B), B, 0, stream>>>(bufA, W2, bufH, N);
    scat_self<64><<<gridFor((long long)N * 64, B), B, 0, stream>>>(bufH, dinv, bufA, N);
    scat_edge<64><<<gridFor((long long)E * 64, B), B, 0, stream>>>(src, dst, bufH, dinv, bufA, E);
    bias_relu<64><<<gridFor((long long)N * 64, B), B, 0, stream>>>(bufA, b2, N);

    // --- layer 3: bufA[N,64] @ W3[64,24] ---  (bias b3 folded into pool_finish)
    mm_kernel<64, 24><<<gridFor((long long)N * 24, B), B, 0, stream>>>(bufA, W3, bufH, N);
    scat_self<24><<<gridFor((long long)N * 24, B), B, 0, stream>>>(bufH, dinv, bufY, N);
    scat_edge<24><<<gridFor((long long)E * 24, B), B, 0, stream>>>(src, dst, bufH, dinv, bufY, E);

    // --- pool: mean over batch, +b3, tanh ---
    hipMemsetAsync(pool, 0, (NGRAPHS * 24 + NGRAPHS) * sizeof(float), stream);
    pool_accum<<<gridFor((long long)N * 24, B), B, 0, stream>>>(bufY, batch, pool, cnt, N);
    pool_finish<<<gridFor(NGRAPHS * 24, B), B, 0, stream>>>(pool, cnt, b3, out);
}

// Round 2
// 813.269 us; speedup vs baseline: 2.3385x; 2.3385x over previous
//
#include <hip/hip_runtime.h>
#include <math.h>

#define NNODES 100000
#define NGRAPHS 64
#define SCAN_TILE 2048

// ---------------- degree histogram (int) ----------------

__global__ void hist_dst(const int* __restrict__ dst, int* __restrict__ cnt, int E) {
    int e = blockIdx.x * blockDim.x + threadIdx.x;
    if (e < E) atomicAdd(&cnt[dst[e]], 1);
}

__global__ void make_dinv(const int* __restrict__ cnt, float* __restrict__ dinv, int n) {
    int i = blockIdx.x * blockDim.x + threadIdx.x;
    if (i < n) dinv[i] = rsqrtf((float)cnt[i] + 1.0f);  // +1 = self loop, always > 0
}

// ---------------- hierarchical exclusive scan of cnt[n] -> rowptr ----------------

__global__ void scan_tile_sums(const int* __restrict__ cnt, int* __restrict__ tileSums, int n) {
    __shared__ int lds[256];
    int base = blockIdx.x * SCAN_TILE;
    int s = 0;
    for (int k = threadIdx.x; k < SCAN_TILE; k += 256) {
        int idx = base + k;
        if (idx < n) s += cnt[idx];
    }
    lds[threadIdx.x] = s;
    __syncthreads();
    for (int off = 128; off > 0; off >>= 1) {
        if (threadIdx.x < off) lds[threadIdx.x] += lds[threadIdx.x + off];
        __syncthreads();
    }
    if (threadIdx.x == 0) tileSums[blockIdx.x] = lds[0];
}

__global__ void scan_tile_offsets(const int* __restrict__ tileSums, int* __restrict__ tileOff,
                                  int numTiles) {
    if (threadIdx.x == 0 && blockIdx.x == 0) {
        int acc = 0;
        for (int t = 0; t < numTiles; ++t) {
            tileOff[t] = acc;
            acc += tileSums[t];
        }
    }
}

__global__ void scan_write(const int* __restrict__ cnt, const int* __restrict__ tileOff,
                           int* __restrict__ rowptr, int n, int E) {
    __shared__ int lds[256];
    int tile = blockIdx.x;
    int start = tile * SCAN_TILE + threadIdx.x * 8;
    int vals[8];
    int s = 0;
#pragma unroll
    for (int k = 0; k < 8; ++k) {
        int idx = start + k;
        vals[k] = (idx < n) ? cnt[idx] : 0;
        s += vals[k];
    }
    lds[threadIdx.x] = s;
    __syncthreads();
    // Hillis-Steele inclusive scan over 256 thread sums
    for (int off = 1; off < 256; off <<= 1) {
        int v = (threadIdx.x >= off) ? lds[threadIdx.x - off] : 0;
        __syncthreads();
        lds[threadIdx.x] += v;
        __syncthreads();
    }
    int excl = ((threadIdx.x > 0) ? lds[threadIdx.x - 1] : 0) + tileOff[tile];
#pragma unroll
    for (int k = 0; k < 8; ++k) {
        int idx = start + k;
        if (idx < n) rowptr[idx] = excl;
        excl += vals[k];
    }
    if (tile == 0 && threadIdx.x == 0) rowptr[n] = E;
}

__global__ void copy_int(const int* __restrict__ a, int* __restrict__ b, int n) {
    int i = blockIdx.x * blockDim.x + threadIdx.x;
    if (i < n) b[i] = a[i];
}

__global__ void csr_fill(const int* __restrict__ src, const int* __restrict__ dst,
                         int* __restrict__ cursor, int* __restrict__ col, int E) {
    int e = blockIdx.x * blockDim.x + threadIdx.x;
    if (e < E) {
        int p = atomicAdd(&cursor[dst[e]], 1);
        col[p] = src[e];
    }
}

// ---------------- dense matmul  out[n,COUT] = x[n,K] @ W[K,COUT] ----------------

template <int K, int COUT>
__global__ void mm_kernel(const float* __restrict__ x, const float* __restrict__ W,
                          float* __restrict__ out, int n) {
    int t = blockIdx.x * blockDim.x + threadIdx.x;
    if (t >= n * COUT) return;
    int i = t / COUT;
    int f = t - i * COUT;
    float acc = 0.0f;
#pragma unroll
    for (int k = 0; k < K; ++k) acc += x[i * K + k] * W[k * COUT + f];
    out[t] = acc;
}

// ---------------- CSR gather aggregation: self-loop + edges + bias + relu ----------------

template <int C, bool RELU>
__global__ void gather_agg(const int* __restrict__ rowptr, const int* __restrict__ col,
                           const float* __restrict__ h, const float* __restrict__ dinv,
                           const float* __restrict__ bias, float* __restrict__ out, int n) {
    int t = blockIdx.x * blockDim.x + threadIdx.x;
    if (t >= n * C) return;
    int i = t / C;
    int c = t - i * C;
    float di = dinv[i];
    float acc = h[t] * di * di;  // self loop
    int beg = rowptr[i];
    int end = rowptr[i + 1];
    for (int j = beg; j < end; ++j) {
        int s = col[j];
        acc += h[s * C + c] * (dinv[s] * di);
    }
    if (bias) acc += bias[c];
    if (RELU) acc = fmaxf(acc, 0.0f);
    out[t] = acc;
}

// ---------------- pooling: LDS two-stage ----------------

__global__ void pool_reduce(const float* __restrict__ y, const int* __restrict__ batch,
                            float* __restrict__ sums, float* __restrict__ cnt, int n) {
    __shared__ float ls[NGRAPHS * 24];
    __shared__ float lc[NGRAPHS];
    for (int k = threadIdx.x; k < NGRAPHS * 24; k += blockDim.x) ls[k] = 0.0f;
    for (int k = threadIdx.x; k < NGRAPHS; k += blockDim.x) lc[k] = 0.0f;
    __syncthreads();
    int total = n * 24;
    int stride = gridDim.x * blockDim.x;
    for (int t = blockIdx.x * blockDim.x + threadIdx.x; t < total; t += stride) {
        int i = t / 24;
        int c = t - i * 24;
        atomicAdd(&ls[batch[i] * 24 + c], y[t]);
    }
    for (int i = blockIdx.x * blockDim.x + threadIdx.x; i < n; i += stride) {
        atomicAdd(&lc[batch[i]], 1.0f);
    }
    __syncthreads();
    for (int k = threadIdx.x; k < NGRAPHS * 24; k += blockDim.x)
        if (ls[k] != 0.0f) atomicAdd(&sums[k], ls[k]);
    for (int k = threadIdx.x; k < NGRAPHS; k += blockDim.x)
        if (lc[k] != 0.0f) atomicAdd(&cnt[k], lc[k]);
}

__global__ void pool_finish(const float* __restrict__ sums, const float* __restrict__ cnt,
                            const float* __restrict__ b3, float* __restrict__ out) {
    int t = blockIdx.x * blockDim.x + threadIdx.x;
    if (t >= NGRAPHS * 24) return;
    int g = t / 24;
    int c = t - g * 24;
    float m = sums[t] / fmaxf(cnt[g], 1.0f) + b3[c];
    out[t] = tanhf(m);
}

// ---------------- launch ----------------

static inline int gridFor(long long total, int block) {
    return (int)((total + block - 1) / block);
}

extern "C" void kernel_launch(void* const* d_in, const int* in_sizes, int n_in,
                              void* d_out, int out_size, void* d_ws, size_t ws_size,
                              hipStream_t stream) {
    const float* pos   = (const float*)d_in[0];
    const int*   ei    = (const int*)d_in[1];
    const int*   batch = (const int*)d_in[2];
    const float* W1    = (const float*)d_in[3];
    const float* b1    = (const float*)d_in[4];
    const float* W2    = (const float*)d_in[5];
    const float* b2    = (const float*)d_in[6];
    const float* W3    = (const float*)d_in[7];
    const float* b3    = (const float*)d_in[8];
    float*       out   = (float*)d_out;

    const int N = NNODES;
    const int E = in_sizes[1] / 2;
    const int* src = ei;
    const int* dst = ei + E;

    // ---- workspace layout ----
    char* p = (char*)d_ws;
    float* dinv    = (float*)p;  p += (size_t)N * sizeof(float);
    float* bufH    = (float*)p;  p += (size_t)N * 64 * sizeof(float);
    float* bufA    = (float*)p;  p += (size_t)N * 64 * sizeof(float);
    float* pool    = (float*)p;  p += (size_t)NGRAPHS * 24 * sizeof(float);
    float* cnt     = (float*)p;  p += (size_t)NGRAPHS * sizeof(float);
    int*   cnt_i   = (int*)p;    p += (size_t)N * sizeof(int);
    int*   rowptr  = (int*)p;    p += (size_t)(N + 1) * sizeof(int);
    int*   cursor  = (int*)p;    p += (size_t)N * sizeof(int);
    int*   tileS   = (int*)p;    p += 64 * sizeof(int);
    int*   tileO   = (int*)p;    p += 64 * sizeof(int);
    int*   col     = (int*)p;    p += (size_t)E * sizeof(int);

    const int B = 256;
    const int numTiles = (N + SCAN_TILE - 1) / SCAN_TILE;

    // ---- degree + dinv + CSR build ----
    hipMemsetAsync(cnt_i, 0, (size_t)N * sizeof(int), stream);
    hist_dst<<<gridFor(E, B), B, 0, stream>>>(dst, cnt_i, E);
    make_dinv<<<gridFor(N, B), B, 0, stream>>>(cnt_i, dinv, N);
    scan_tile_sums<<<numTiles, 256, 0, stream>>>(cnt_i, tileS, N);
    scan_tile_offsets<<<1, 64, 0, stream>>>(tileS, tileO, numTiles);
    scan_write<<<numTiles, 256, 0, stream>>>(cnt_i, tileO, rowptr, N, E);
    copy_int<<<gridFor(N, B), B, 0, stream>>>(rowptr, cursor, N);
    csr_fill<<<gridFor(E, B), B, 0, stream>>>(src, dst, cursor, col, E);

    // ---- layer 1: pos[N,3] @ W1 -> aggregate -> relu ----
    mm_kernel<3, 64><<<gridFor((long long)N * 64, B), B, 0, stream>>>(pos, W1, bufH, N);
    gather_agg<64, true><<<gridFor((long long)N * 64, B), B, 0, stream>>>(
        rowptr, col, bufH, dinv, b1, bufA, N);

    // ---- layer 2 ----
    mm_kernel<64, 64><<<gridFor((long long)N * 64, B), B, 0, stream>>>(bufA, W2, bufH, N);
    gather_agg<64, true><<<gridFor((long long)N * 64, B), B, 0, stream>>>(
        rowptr, col, bufH, dinv, b2, bufA, N);

    // ---- layer 3 (no relu; b3 folded into pool_finish). Output reuses bufA. ----
    mm_kernel<64, 24><<<gridFor((long long)N * 24, B), B, 0, stream>>>(bufA, W3, bufH, N);
    gather_agg<24, false><<<gridFor((long long)N * 24, B), B, 0, stream>>>(
        rowptr, col, bufH, dinv, (const float*)nullptr, bufA, N);

    // ---- pool ----
    hipMemsetAsync(pool, 0, (size_t)(NGRAPHS * 24 + NGRAPHS) * sizeof(float), stream);
    pool_reduce<<<256, 256, 0, stream>>>(bufA, batch, pool, cnt, N);
    pool_finish<<<gridFor(NGRAPHS * 24, B), B, 0, stream>>>(pool, cnt, b3, out);
}

// Round 3
// 572.456 us; speedup vs baseline: 3.3223x; 1.4207x over previous
//
#include <hip/hip_runtime.h>
#include <math.h>

#define NNODES 100000
#define NGRAPHS 64
#define SCAN_TILE 2048

// ---------------- degree histogram (int) ----------------

__global__ void hist_dst(const int* __restrict__ dst, int* __restrict__ cnt, int E) {
    int e = blockIdx.x * blockDim.x + threadIdx.x;
    if (e < E) atomicAdd(&cnt[dst[e]], 1);
}

__global__ void make_dinv(const int* __restrict__ cnt, float* __restrict__ dinv, int n) {
    int i = blockIdx.x * blockDim.x + threadIdx.x;
    if (i < n) dinv[i] = rsqrtf((float)cnt[i] + 1.0f);  // +1 = self loop, always > 0
}

// ---------------- hierarchical exclusive scan of cnt[n] -> rowptr (+cursor copy) ----------------

__global__ void scan_tile_sums(const int* __restrict__ cnt, int* __restrict__ tileSums, int n) {
    __shared__ int lds[256];
    int base = blockIdx.x * SCAN_TILE;
    int s = 0;
    for (int k = threadIdx.x; k < SCAN_TILE; k += 256) {
        int idx = base + k;
        if (idx < n) s += cnt[idx];
    }
    lds[threadIdx.x] = s;
    __syncthreads();
    for (int off = 128; off > 0; off >>= 1) {
        if (threadIdx.x < off) lds[threadIdx.x] += lds[threadIdx.x + off];
        __syncthreads();
    }
    if (threadIdx.x == 0) tileSums[blockIdx.x] = lds[0];
}

__global__ void scan_tile_offsets(const int* __restrict__ tileSums, int* __restrict__ tileOff,
                                  int numTiles) {
    if (threadIdx.x == 0 && blockIdx.x == 0) {
        int acc = 0;
        for (int t = 0; t < numTiles; ++t) {
            tileOff[t] = acc;
            acc += tileSums[t];
        }
    }
}

__global__ void scan_write(const int* __restrict__ cnt, const int* __restrict__ tileOff,
                           int* __restrict__ rowptr, int* __restrict__ cursor, int n, int E) {
    __shared__ int lds[256];
    int tile = blockIdx.x;
    int start = tile * SCAN_TILE + threadIdx.x * 8;
    int vals[8];
    int s = 0;
#pragma unroll
    for (int k = 0; k < 8; ++k) {
        int idx = start + k;
        vals[k] = (idx < n) ? cnt[idx] : 0;
        s += vals[k];
    }
    lds[threadIdx.x] = s;
    __syncthreads();
    for (int off = 1; off < 256; off <<= 1) {
        int v = (threadIdx.x >= off) ? lds[threadIdx.x - off] : 0;
        __syncthreads();
        lds[threadIdx.x] += v;
        __syncthreads();
    }
    int excl = ((threadIdx.x > 0) ? lds[threadIdx.x - 1] : 0) + tileOff[tile];
#pragma unroll
    for (int k = 0; k < 8; ++k) {
        int idx = start + k;
        if (idx < n) { rowptr[idx] = excl; cursor[idx] = excl; }
        excl += vals[k];
    }
    if (tile == 0 && threadIdx.x == 0) rowptr[n] = E;
}

__global__ void csr_fill(const int* __restrict__ src, const int* __restrict__ dst,
                         int* __restrict__ cursor, int* __restrict__ col, int E) {
    int e = blockIdx.x * blockDim.x + threadIdx.x;
    if (e < E) {
        int p = atomicAdd(&cursor[dst[e]], 1);
        col[p] = src[e];
    }
}

// ---------------- pos padding [N,3] -> float4 ----------------

__global__ void pad_pos(const float* __restrict__ pos, float4* __restrict__ p4, int n) {
    int i = blockIdx.x * blockDim.x + threadIdx.x;
    if (i < n) {
        float4 v;
        v.x = pos[i * 3 + 0];
        v.y = pos[i * 3 + 1];
        v.z = pos[i * 3 + 2];
        v.w = 0.0f;
        p4[i] = v;
    }
}

// ---------------- layer-1: aggregate pos (C=3 as float4), one thread per node ----------------

__global__ void gather_pos(const int* __restrict__ rowptr, const int* __restrict__ col,
                           const float4* __restrict__ p4, const float* __restrict__ dinv,
                           float4* __restrict__ outp, int n) {
    int i = blockIdx.x * blockDim.x + threadIdx.x;
    if (i >= n) return;
    float di = dinv[i];
    int beg = rowptr[i];
    int end = rowptr[i + 1];
    float4 sv = p4[i];
    // self-loop contributes h*di; final multiply by di outside
    float ax0 = sv.x * di, ay0 = sv.y * di, az0 = sv.z * di;
    float ax1 = 0, ay1 = 0, az1 = 0;
    float ax2 = 0, ay2 = 0, az2 = 0;
    float ax3 = 0, ay3 = 0, az3 = 0;
    int j = beg;
    for (; j + 4 <= end; j += 4) {
        int s0 = col[j], s1 = col[j + 1], s2 = col[j + 2], s3 = col[j + 3];
        float w0 = dinv[s0], w1 = dinv[s1], w2 = dinv[s2], w3 = dinv[s3];
        float4 v0 = p4[s0], v1 = p4[s1], v2 = p4[s2], v3 = p4[s3];
        ax0 += v0.x * w0; ay0 += v0.y * w0; az0 += v0.z * w0;
        ax1 += v1.x * w1; ay1 += v1.y * w1; az1 += v1.z * w1;
        ax2 += v2.x * w2; ay2 += v2.y * w2; az2 += v2.z * w2;
        ax3 += v3.x * w3; ay3 += v3.y * w3; az3 += v3.z * w3;
    }
    for (; j < end; ++j) {
        int s = col[j];
        float w = dinv[s];
        float4 v = p4[s];
        ax1 += v.x * w; ay1 += v.y * w; az1 += v.z * w;
    }
    float4 o;
    o.x = di * ((ax0 + ax1) + (ax2 + ax3));
    o.y = di * ((ay0 + ay1) + (ay2 + ay3));
    o.z = di * ((az0 + az1) + (az2 + az3));
    o.w = 0.0f;
    outp[i] = o;
}

// layer-1 matmul: out[i,f] = relu(aggP[i] . W1[:,f] + b1[f])
__global__ void mm1_fused(const float4* __restrict__ aggP, const float* __restrict__ W1,
                          const float* __restrict__ b1, float* __restrict__ out, int n) {
    int t = blockIdx.x * blockDim.x + threadIdx.x;
    if (t >= n * 64) return;
    int i = t >> 6;
    int f = t & 63;
    float4 x = aggP[i];
    float acc = b1[f] + x.x * W1[f] + x.y * W1[64 + f] + x.z * W1[128 + f];
    out[t] = fmaxf(acc, 0.0f);
}

// ---------------- dense matmul  out[n,COUT] = x[n,K] @ W[K,COUT] ----------------

template <int K, int COUT>
__global__ void mm_kernel(const float* __restrict__ x, const float* __restrict__ W,
                          float* __restrict__ out, int n) {
    int t = blockIdx.x * blockDim.x + threadIdx.x;
    if (t >= n * COUT) return;
    int i = t / COUT;
    int f = t - i * COUT;
    float acc = 0.0f;
#pragma unroll
    for (int k = 0; k < K; ++k) acc += x[i * K + k] * W[k * COUT + f];
    out[t] = acc;
}

// ---------------- CSR gather aggregation, 4-way edge ILP ----------------

template <int C, bool RELU, bool BIAS>
__global__ void gather_agg(const int* __restrict__ rowptr, const int* __restrict__ col,
                           const float* __restrict__ h, const float* __restrict__ dinv,
                           const float* __restrict__ bias, float* __restrict__ out, int n) {
    int t = blockIdx.x * blockDim.x + threadIdx.x;
    if (t >= n * C) return;
    int i = t / C;
    int c = t - i * C;
    float di = dinv[i];
    int beg = rowptr[i];
    int end = rowptr[i + 1];
    // self-loop folded: total = di * (h_self*di + sum h[s]*dinv[s])
    float a0 = h[t] * di;
    float a1 = 0.0f, a2 = 0.0f, a3 = 0.0f;
    int j = beg;
    for (; j + 4 <= end; j += 4) {
        int s0 = col[j], s1 = col[j + 1], s2 = col[j + 2], s3 = col[j + 3];
        float w0 = dinv[s0], w1 = dinv[s1], w2 = dinv[s2], w3 = dinv[s3];
        a0 += h[(size_t)s0 * C + c] * w0;
        a1 += h[(size_t)s1 * C + c] * w1;
        a2 += h[(size_t)s2 * C + c] * w2;
        a3 += h[(size_t)s3 * C + c] * w3;
    }
    for (; j < end; ++j) {
        int s = col[j];
        a1 += h[(size_t)s * C + c] * dinv[s];
    }
    float acc = di * ((a0 + a1) + (a2 + a3));
    if (BIAS) acc += bias[c];
    if (RELU) acc = fmaxf(acc, 0.0f);
    out[t] = acc;
}

// ---------------- pooling: LDS two-stage ----------------

__global__ void pool_reduce(const float* __restrict__ y, const int* __restrict__ batch,
                            float* __restrict__ sums, float* __restrict__ cnt, int n) {
    __shared__ float ls[NGRAPHS * 24];
    __shared__ float lc[NGRAPHS];
    for (int k = threadIdx.x; k < NGRAPHS * 24; k += blockDim.x) ls[k] = 0.0f;
    for (int k = threadIdx.x; k < NGRAPHS; k += blockDim.x) lc[k] = 0.0f;
    __syncthreads();
    int total = n * 24;
    int stride = gridDim.x * blockDim.x;
    for (int t = blockIdx.x * blockDim.x + threadIdx.x; t < total; t += stride) {
        int i = t / 24;
        int c = t - i * 24;
        atomicAdd(&ls[batch[i] * 24 + c], y[t]);
    }
    for (int i = blockIdx.x * blockDim.x + threadIdx.x; i < n; i += stride) {
        atomicAdd(&lc[batch[i]], 1.0f);
    }
    __syncthreads();
    for (int k = threadIdx.x; k < NGRAPHS * 24; k += blockDim.x)
        if (ls[k] != 0.0f) atomicAdd(&sums[k], ls[k]);
    for (int k = threadIdx.x; k < NGRAPHS; k += blockDim.x)
        if (lc[k] != 0.0f) atomicAdd(&cnt[k], lc[k]);
}

__global__ void pool_finish(const float* __restrict__ sums, const float* __restrict__ cnt,
                            const float* __restrict__ b3, float* __restrict__ out) {
    int t = blockIdx.x * blockDim.x + threadIdx.x;
    if (t >= NGRAPHS * 24) return;
    int g = t / 24;
    int c = t - g * 24;
    float m = sums[t] / fmaxf(cnt[g], 1.0f) + b3[c];
    out[t] = tanhf(m);
}

// ---------------- launch ----------------

static inline int gridFor(long long total, int block) {
    return (int)((total + block - 1) / block);
}

extern "C" void kernel_launch(void* const* d_in, const int* in_sizes, int n_in,
                              void* d_out, int out_size, void* d_ws, size_t ws_size,
                              hipStream_t stream) {
    const float* pos   = (const float*)d_in[0];
    const int*   ei    = (const int*)d_in[1];
    const int*   batch = (const int*)d_in[2];
    const float* W1    = (const float*)d_in[3];
    const float* b1    = (const float*)d_in[4];
    const float* W2    = (const float*)d_in[5];
    const float* b2    = (const float*)d_in[6];
    const float* W3    = (const float*)d_in[7];
    const float* b3    = (const float*)d_in[8];
    float*       out   = (float*)d_out;

    const int N = NNODES;
    const int E = in_sizes[1] / 2;
    const int* src = ei;
    const int* dst = ei + E;

    // ---- workspace layout ----
    char* p = (char*)d_ws;
    float*  dinv   = (float*)p;   p += (size_t)N * sizeof(float);
    float4* pos4   = (float4*)p;  p += (size_t)N * sizeof(float4);
    float4* aggP   = (float4*)p;  p += (size_t)N * sizeof(float4);
    float*  bufH   = (float*)p;   p += (size_t)N * 64 * sizeof(float);
    float*  bufA   = (float*)p;   p += (size_t)N * 64 * sizeof(float);
    float*  pool   = (float*)p;   p += (size_t)NGRAPHS * 24 * sizeof(float);
    float*  cnt    = (float*)p;   p += (size_t)NGRAPHS * sizeof(float);
    int*    cnt_i  = (int*)p;     p += (size_t)N * sizeof(int);
    int*    rowptr = (int*)p;     p += (size_t)(N + 1) * sizeof(int);
    int*    cursor = (int*)p;     p += (size_t)N * sizeof(int);
    int*    tileS  = (int*)p;     p += 64 * sizeof(int);
    int*    tileO  = (int*)p;     p += 64 * sizeof(int);
    int*    col    = (int*)p;     p += (size_t)E * sizeof(int);

    const int B = 256;
    const int numTiles = (N + SCAN_TILE - 1) / SCAN_TILE;

    // ---- degree + dinv + CSR build ----
    hipMemsetAsync(cnt_i, 0, (size_t)N * sizeof(int), stream);
    hist_dst<<<gridFor(E, B), B, 0, stream>>>(dst, cnt_i, E);
    make_dinv<<<gridFor(N, B), B, 0, stream>>>(cnt_i, dinv, N);
    scan_tile_sums<<<numTiles, 256, 0, stream>>>(cnt_i, tileS, N);
    scan_tile_offsets<<<1, 64, 0, stream>>>(tileS, tileO, numTiles);
    scan_write<<<numTiles, 256, 0, stream>>>(cnt_i, tileO, rowptr, cursor, N, E);
    csr_fill<<<gridFor(E, B), B, 0, stream>>>(src, dst, cursor, col, E);

    // ---- layer 1: agg(pos) @ W1 + b1, relu  (agg is linear, commute with matmul) ----
    pad_pos<<<gridFor(N, B), B, 0, stream>>>(pos, pos4, N);
    gather_pos<<<gridFor(N, B), B, 0, stream>>>(rowptr, col, pos4, dinv, aggP, N);
    mm1_fused<<<gridFor((long long)N * 64, B), B, 0, stream>>>(aggP, W1, b1, bufA, N);

    // ---- layer 2 ----
    mm_kernel<64, 64><<<gridFor((long long)N * 64, B), B, 0, stream>>>(bufA, W2, bufH, N);
    gather_agg<64, true, true><<<gridFor((long long)N * 64, B), B, 0, stream>>>(
        rowptr, col, bufH, dinv, b2, bufA, N);

    // ---- layer 3 (no relu; b3 folded into pool_finish) ----
    mm_kernel<64, 24><<<gridFor((long long)N * 24, B), B, 0, stream>>>(bufA, W3, bufH, N);
    gather_agg<24, false, false><<<gridFor((long long)N * 24, B), B, 0, stream>>>(
        rowptr, col, bufH, dinv, (const float*)nullptr, bufA, N);

    // ---- pool ----
    hipMemsetAsync(pool, 0, (size_t)(NGRAPHS * 24 + NGRAPHS) * sizeof(float), stream);
    pool_reduce<<<256, 256, 0, stream>>>(bufA, batch, pool, cnt, N);
    pool_finish<<<gridFor(NGRAPHS * 24, B), B, 0, stream>>>(pool, cnt, b3, out);
}

// Round 4
// 435.085 us; speedup vs baseline: 4.3712x; 1.3157x over previous
//
#include <hip/hip_runtime.h>
#include <math.h>

#define NNODES 100000
#define NGRAPHS 64
#define SCAN_TILE 2048

// ---------------- degree histogram (int), 4-way ILP ----------------

__global__ void hist_dst(const int* __restrict__ dst, int* __restrict__ cnt, int E) {
    int base = blockIdx.x * blockDim.x * 4 + threadIdx.x;
    int B = blockDim.x;
#pragma unroll
    for (int k = 0; k < 4; ++k) {
        int e = base + k * B;
        if (e < E) atomicAdd(&cnt[dst[e]], 1);
    }
}

__global__ void make_dinv(const int* __restrict__ cnt, float* __restrict__ dinv, int n) {
    int i = blockIdx.x * blockDim.x + threadIdx.x;
    if (i < n) dinv[i] = rsqrtf((float)cnt[i] + 1.0f);  // +1 = self loop, always > 0
}

// ---------------- hierarchical exclusive scan of cnt[n] -> rowptr (+cursor copy) ----------------

__global__ void scan_tile_sums(const int* __restrict__ cnt, int* __restrict__ tileSums, int n) {
    __shared__ int lds[256];
    int base = blockIdx.x * SCAN_TILE;
    int s = 0;
    for (int k = threadIdx.x; k < SCAN_TILE; k += 256) {
        int idx = base + k;
        if (idx < n) s += cnt[idx];
    }
    lds[threadIdx.x] = s;
    __syncthreads();
    for (int off = 128; off > 0; off >>= 1) {
        if (threadIdx.x < off) lds[threadIdx.x] += lds[threadIdx.x + off];
        __syncthreads();
    }
    if (threadIdx.x == 0) tileSums[blockIdx.x] = lds[0];
}

__global__ void scan_tile_offsets(const int* __restrict__ tileSums, int* __restrict__ tileOff,
                                  int numTiles) {
    if (threadIdx.x == 0 && blockIdx.x == 0) {
        int acc = 0;
        for (int t = 0; t < numTiles; ++t) {
            tileOff[t] = acc;
            acc += tileSums[t];
        }
    }
}

__global__ void scan_write(const int* __restrict__ cnt, const int* __restrict__ tileOff,
                           int* __restrict__ rowptr, int* __restrict__ cursor, int n, int E) {
    __shared__ int lds[256];
    int tile = blockIdx.x;
    int start = tile * SCAN_TILE + threadIdx.x * 8;
    int vals[8];
    int s = 0;
#pragma unroll
    for (int k = 0; k < 8; ++k) {
        int idx = start + k;
        vals[k] = (idx < n) ? cnt[idx] : 0;
        s += vals[k];
    }
    lds[threadIdx.x] = s;
    __syncthreads();
    for (int off = 1; off < 256; off <<= 1) {
        int v = (threadIdx.x >= off) ? lds[threadIdx.x - off] : 0;
        __syncthreads();
        lds[threadIdx.x] += v;
        __syncthreads();
    }
    int excl = ((threadIdx.x > 0) ? lds[threadIdx.x - 1] : 0) + tileOff[tile];
#pragma unroll
    for (int k = 0; k < 8; ++k) {
        int idx = start + k;
        if (idx < n) { rowptr[idx] = excl; cursor[idx] = excl; }
        excl += vals[k];
    }
    if (tile == 0 && threadIdx.x == 0) rowptr[n] = E;
}

// ---------------- CSR fill, 4-way ILP (latency-bound: 4 atomic chains in flight) ----------------

__global__ void csr_fill(const int* __restrict__ src, const int* __restrict__ dst,
                         int* __restrict__ cursor, int* __restrict__ col, int E) {
    int base = blockIdx.x * blockDim.x * 4 + threadIdx.x;
    int B = blockDim.x;
    int e0 = base, e1 = base + B, e2 = base + 2 * B, e3 = base + 3 * B;
    int d0 = 0, d1 = 0, d2 = 0, d3 = 0, s0 = 0, s1 = 0, s2 = 0, s3 = 0;
    if (e0 < E) { d0 = dst[e0]; s0 = src[e0]; }
    if (e1 < E) { d1 = dst[e1]; s1 = src[e1]; }
    if (e2 < E) { d2 = dst[e2]; s2 = src[e2]; }
    if (e3 < E) { d3 = dst[e3]; s3 = src[e3]; }
    int p0 = 0, p1 = 0, p2 = 0, p3 = 0;
    if (e0 < E) p0 = atomicAdd(&cursor[d0], 1);
    if (e1 < E) p1 = atomicAdd(&cursor[d1], 1);
    if (e2 < E) p2 = atomicAdd(&cursor[d2], 1);
    if (e3 < E) p3 = atomicAdd(&cursor[d3], 1);
    if (e0 < E) col[p0] = s0;
    if (e1 < E) col[p1] = s1;
    if (e2 < E) col[p2] = s2;
    if (e3 < E) col[p3] = s3;
}

// ---------------- pos padding [N,3] -> float4 ----------------

__global__ void pad_pos(const float* __restrict__ pos, float4* __restrict__ p4, int n) {
    int i = blockIdx.x * blockDim.x + threadIdx.x;
    if (i < n) {
        float4 v;
        v.x = pos[i * 3 + 0];
        v.y = pos[i * 3 + 1];
        v.z = pos[i * 3 + 2];
        v.w = 0.0f;
        p4[i] = v;
    }
}

// ---------------- layer-1: aggregate pos (C=3 as float4), one thread per node ----------------

__global__ void gather_pos(const int* __restrict__ rowptr, const int* __restrict__ col,
                           const float4* __restrict__ p4, const float* __restrict__ dinv,
                           float4* __restrict__ outp, int n) {
    int i = blockIdx.x * blockDim.x + threadIdx.x;
    if (i >= n) return;
    float di = dinv[i];
    int beg = rowptr[i];
    int end = rowptr[i + 1];
    float4 sv = p4[i];
    float ax0 = sv.x * di, ay0 = sv.y * di, az0 = sv.z * di;
    float ax1 = 0, ay1 = 0, az1 = 0;
    float ax2 = 0, ay2 = 0, az2 = 0;
    float ax3 = 0, ay3 = 0, az3 = 0;
    int j = beg;
    for (; j + 4 <= end; j += 4) {
        int s0 = col[j], s1 = col[j + 1], s2 = col[j + 2], s3 = col[j + 3];
        float w0 = dinv[s0], w1 = dinv[s1], w2 = dinv[s2], w3 = dinv[s3];
        float4 v0 = p4[s0], v1 = p4[s1], v2 = p4[s2], v3 = p4[s3];
        ax0 += v0.x * w0; ay0 += v0.y * w0; az0 += v0.z * w0;
        ax1 += v1.x * w1; ay1 += v1.y * w1; az1 += v1.z * w1;
        ax2 += v2.x * w2; ay2 += v2.y * w2; az2 += v2.z * w2;
        ax3 += v3.x * w3; ay3 += v3.y * w3; az3 += v3.z * w3;
    }
    for (; j < end; ++j) {
        int s = col[j];
        float w = dinv[s];
        float4 v = p4[s];
        ax1 += v.x * w; ay1 += v.y * w; az1 += v.z * w;
    }
    float4 o;
    o.x = di * ((ax0 + ax1) + (ax2 + ax3));
    o.y = di * ((ay0 + ay1) + (ay2 + ay3));
    o.z = di * ((az0 + az1) + (az2 + az3));
    o.w = 0.0f;
    outp[i] = o;
}

// layer-1 matmul: out[i,f] = relu(aggP[i] . W1[:,f] + b1[f])
__global__ void mm1_fused(const float4* __restrict__ aggP, const float* __restrict__ W1,
                          const float* __restrict__ b1, float* __restrict__ out, int n) {
    int t = blockIdx.x * blockDim.x + threadIdx.x;
    if (t >= n * 64) return;
    int i = t >> 6;
    int f = t & 63;
    float4 x = aggP[i];
    float acc = b1[f] + x.x * W1[f] + x.y * W1[64 + f] + x.z * W1[128 + f];
    out[t] = fmaxf(acc, 0.0f);
}

// ---------------- LDS-tiled matmul: out[n,COUT] = x[n,64] @ W[64,COUT] ----------------
// F4 = COUT/4 output float4 groups; TY row-groups; each thread: 4 rows x 4 cols.
// Block = F4*TY threads; tile = TY*4 rows.

template <int F4, int TY>
__global__ void mm_tiled(const float4* __restrict__ x4, const float* __restrict__ W,
                         float4* __restrict__ out4, int n) {
    constexpr int ROWS = TY * 4;
    __shared__ float xs[ROWS][65];       // +1 pad: bank = (r+k)%32, conflict-free
    __shared__ float4 ws[64 * F4];
    const int tid = threadIdx.x;
    const int rowBase = blockIdx.x * ROWS;
    const int BT = F4 * TY;

    for (int idx = tid; idx < ROWS * 16; idx += BT) {
        int r = idx >> 4;
        int k4 = idx & 15;
        int gr = rowBase + r;
        float4 v = (gr < n) ? x4[(size_t)gr * 16 + k4] : make_float4(0, 0, 0, 0);
        xs[r][k4 * 4 + 0] = v.x;
        xs[r][k4 * 4 + 1] = v.y;
        xs[r][k4 * 4 + 2] = v.z;
        xs[r][k4 * 4 + 3] = v.w;
    }
    const float4* W4 = (const float4*)W;
    for (int idx = tid; idx < 64 * F4; idx += BT) ws[idx] = W4[idx];
    __syncthreads();

    const int f4 = tid % F4;
    const int r0 = (tid / F4) * 4;
    float4 a0 = make_float4(0, 0, 0, 0), a1 = a0, a2 = a0, a3 = a0;
#pragma unroll 4
    for (int k = 0; k < 64; ++k) {
        float4 wv = ws[k * F4 + f4];
        float xa = xs[r0 + 0][k];
        float xb = xs[r0 + 1][k];
        float xc = xs[r0 + 2][k];
        float xd = xs[r0 + 3][k];
        a0.x += wv.x * xa; a0.y += wv.y * xa; a0.z += wv.z * xa; a0.w += wv.w * xa;
        a1.x += wv.x * xb; a1.y += wv.y * xb; a1.z += wv.z * xb; a1.w += wv.w * xb;
        a2.x += wv.x * xc; a2.y += wv.y * xc; a2.z += wv.z * xc; a2.w += wv.w * xc;
        a3.x += wv.x * xd; a3.y += wv.y * xd; a3.z += wv.z * xd; a3.w += wv.w * xd;
    }
    if (rowBase + r0 + 0 < n) out4[(size_t)(rowBase + r0 + 0) * F4 + f4] = a0;
    if (rowBase + r0 + 1 < n) out4[(size_t)(rowBase + r0 + 1) * F4 + f4] = a1;
    if (rowBase + r0 + 2 < n) out4[(size_t)(rowBase + r0 + 2) * F4 + f4] = a2;
    if (rowBase + r0 + 3 < n) out4[(size_t)(rowBase + r0 + 3) * F4 + f4] = a3;
}

// ---------------- CSR gather aggregation, float4 channels + 4-way edge ILP ----------------

template <int C4, bool RELU, bool BIAS>
__global__ void gather_agg4(const int* __restrict__ rowptr, const int* __restrict__ col,
                            const float4* __restrict__ h, const float* __restrict__ dinv,
                            const float* __restrict__ bias, float4* __restrict__ out, int n) {
    int t = blockIdx.x * blockDim.x + threadIdx.x;
    if (t >= n * C4) return;
    int i = t / C4;
    int c4 = t - i * C4;
    float di = dinv[i];
    int beg = rowptr[i];
    int end = rowptr[i + 1];
    float4 hs = h[t];
    float4 a0, a1, a2, a3;
    a0.x = hs.x * di; a0.y = hs.y * di; a0.z = hs.z * di; a0.w = hs.w * di;
    a1 = make_float4(0, 0, 0, 0); a2 = a1; a3 = a1;
    int j = beg;
    for (; j + 4 <= end; j += 4) {
        int s0 = col[j], s1 = col[j + 1], s2 = col[j + 2], s3 = col[j + 3];
        float w0 = dinv[s0], w1 = dinv[s1], w2 = dinv[s2], w3 = dinv[s3];
        float4 v0 = h[(size_t)s0 * C4 + c4];
        float4 v1 = h[(size_t)s1 * C4 + c4];
        float4 v2 = h[(size_t)s2 * C4 + c4];
        float4 v3 = h[(size_t)s3 * C4 + c4];
        a0.x += v0.x * w0; a0.y += v0.y * w0; a0.z += v0.z * w0; a0.w += v0.w * w0;
        a1.x += v1.x * w1; a1.y += v1.y * w1; a1.z += v1.z * w1; a1.w += v1.w * w1;
        a2.x += v2.x * w2; a2.y += v2.y * w2; a2.z += v2.z * w2; a2.w += v2.w * w2;
        a3.x += v3.x * w3; a3.y += v3.y * w3; a3.z += v3.z * w3; a3.w += v3.w * w3;
    }
    for (; j < end; ++j) {
        int s = col[j];
        float w = dinv[s];
        float4 v = h[(size_t)s * C4 + c4];
        a1.x += v.x * w; a1.y += v.y * w; a1.z += v.z * w; a1.w += v.w * w;
    }
    float4 acc;
    acc.x = di * ((a0.x + a1.x) + (a2.x + a3.x));
    acc.y = di * ((a0.y + a1.y) + (a2.y + a3.y));
    acc.z = di * ((a0.z + a1.z) + (a2.z + a3.z));
    acc.w = di * ((a0.w + a1.w) + (a2.w + a3.w));
    if (BIAS) {
        float4 bv = ((const float4*)bias)[c4];
        acc.x += bv.x; acc.y += bv.y; acc.z += bv.z; acc.w += bv.w;
    }
    if (RELU) {
        acc.x = fmaxf(acc.x, 0.0f); acc.y = fmaxf(acc.y, 0.0f);
        acc.z = fmaxf(acc.z, 0.0f); acc.w = fmaxf(acc.w, 0.0f);
    }
    out[t] = acc;
}

// ---------------- pooling: LDS two-stage ----------------

__global__ void pool_reduce(const float* __restrict__ y, const int* __restrict__ batch,
                            float* __restrict__ sums, float* __restrict__ cnt, int n) {
    __shared__ float ls[NGRAPHS * 24];
    __shared__ float lc[NGRAPHS];
    for (int k = threadIdx.x; k < NGRAPHS * 24; k += blockDim.x) ls[k] = 0.0f;
    for (int k = threadIdx.x; k < NGRAPHS; k += blockDim.x) lc[k] = 0.0f;
    __syncthreads();
    int total = n * 24;
    int stride = gridDim.x * blockDim.x;
    for (int t = blockIdx.x * blockDim.x + threadIdx.x; t < total; t += stride) {
        int i = t / 24;
        int c = t - i * 24;
        atomicAdd(&ls[batch[i] * 24 + c], y[t]);
    }
    for (int i = blockIdx.x * blockDim.x + threadIdx.x; i < n; i += stride) {
        atomicAdd(&lc[batch[i]], 1.0f);
    }
    __syncthreads();
    for (int k = threadIdx.x; k < NGRAPHS * 24; k += blockDim.x)
        if (ls[k] != 0.0f) atomicAdd(&sums[k], ls[k]);
    for (int k = threadIdx.x; k < NGRAPHS; k += blockDim.x)
        if (lc[k] != 0.0f) atomicAdd(&cnt[k], lc[k]);
}

__global__ void pool_finish(const float* __restrict__ sums, const float* __restrict__ cnt,
                            const float* __restrict__ b3, float* __restrict__ out) {
    int t = blockIdx.x * blockDim.x + threadIdx.x;
    if (t >= NGRAPHS * 24) return;
    int g = t / 24;
    int c = t - g * 24;
    float m = sums[t] / fmaxf(cnt[g], 1.0f) + b3[c];
    out[t] = tanhf(m);
}

// ---------------- launch ----------------

static inline int gridFor(long long total, int block) {
    return (int)((total + block - 1) / block);
}

extern "C" void kernel_launch(void* const* d_in, const int* in_sizes, int n_in,
                              void* d_out, int out_size, void* d_ws, size_t ws_size,
                              hipStream_t stream) {
    const float* pos   = (const float*)d_in[0];
    const int*   ei    = (const int*)d_in[1];
    const int*   batch = (const int*)d_in[2];
    const float* W1    = (const float*)d_in[3];
    const float* b1    = (const float*)d_in[4];
    const float* W2    = (const float*)d_in[5];
    const float* b2    = (const float*)d_in[6];
    const float* W3    = (const float*)d_in[7];
    const float* b3    = (const float*)d_in[8];
    float*       out   = (float*)d_out;

    const int N = NNODES;
    const int E = in_sizes[1] / 2;
    const int* src = ei;
    const int* dst = ei + E;

    // ---- workspace layout (all float4 chunks 16B-aligned) ----
    char* p = (char*)d_ws;
    float*  dinv   = (float*)p;   p += (size_t)N * sizeof(float);
    float4* pos4   = (float4*)p;  p += (size_t)N * sizeof(float4);
    float4* aggP   = (float4*)p;  p += (size_t)N * sizeof(float4);
    float*  bufH   = (float*)p;   p += (size_t)N * 64 * sizeof(float);
    float*  bufA   = (float*)p;   p += (size_t)N * 64 * sizeof(float);
    float*  pool   = (float*)p;   p += (size_t)NGRAPHS * 24 * sizeof(float);
    float*  cnt    = (float*)p;   p += (size_t)NGRAPHS * sizeof(float);
    int*    cnt_i  = (int*)p;     p += (size_t)N * sizeof(int);
    int*    rowptr = (int*)p;     p += (size_t)(N + 1) * sizeof(int);
    int*    cursor = (int*)p;     p += (size_t)N * sizeof(int);
    int*    tileS  = (int*)p;     p += 64 * sizeof(int);
    int*    tileO  = (int*)p;     p += 64 * sizeof(int);
    int*    col    = (int*)p;     p += (size_t)E * sizeof(int);

    const int B = 256;
    const int numTiles = (N + SCAN_TILE - 1) / SCAN_TILE;

    // ---- degree + dinv + CSR build ----
    hipMemsetAsync(cnt_i, 0, (size_t)N * sizeof(int), stream);
    hist_dst<<<gridFor(E, B * 4), B, 0, stream>>>(dst, cnt_i, E);
    make_dinv<<<gridFor(N, B), B, 0, stream>>>(cnt_i, dinv, N);
    scan_tile_sums<<<numTiles, 256, 0, stream>>>(cnt_i, tileS, N);
    scan_tile_offsets<<<1, 64, 0, stream>>>(tileS, tileO, numTiles);
    scan_write<<<numTiles, 256, 0, stream>>>(cnt_i, tileO, rowptr, cursor, N, E);
    csr_fill<<<gridFor(E, B * 4), B, 0, stream>>>(src, dst, cursor, col, E);

    // ---- layer 1: agg(pos) @ W1 + b1, relu  (aggregation commutes with matmul) ----
    pad_pos<<<gridFor(N, B), B, 0, stream>>>(pos, pos4, N);
    gather_pos<<<gridFor(N, B), B, 0, stream>>>(rowptr, col, pos4, dinv, aggP, N);
    mm1_fused<<<gridFor((long long)N * 64, B), B, 0, stream>>>(aggP, W1, b1, bufA, N);

    // ---- layer 2: h2 = relu(agg(h1 @ W2) + b2) ----
    mm_tiled<16, 16><<<gridFor(N, 64), 256, 0, stream>>>(
        (const float4*)bufA, W2, (float4*)bufH, N);
    gather_agg4<16, true, true><<<gridFor((long long)N * 16, B), B, 0, stream>>>(
        rowptr, col, (const float4*)bufH, dinv, b2, (float4*)bufA, N);

    // ---- layer 3: y = agg(h2 @ W3)  (b3 folded into pool_finish) ----
    mm_tiled<6, 32><<<gridFor(N, 128), 192, 0, stream>>>(
        (const float4*)bufA, W3, (float4*)bufH, N);
    gather_agg4<6, false, false><<<gridFor((long long)N * 6, B), B, 0, stream>>>(
        rowptr, col, (const float4*)bufH, dinv, (const float*)nullptr, (float4*)bufA, N);

    // ---- pool ----
    hipMemsetAsync(pool, 0, (size_t)(NGRAPHS * 24 + NGRAPHS) * sizeof(float), stream);
    pool_reduce<<<256, 256, 0, stream>>>(bufA, batch, pool, cnt, N);
    pool_finish<<<gridFor(NGRAPHS * 24, B), B, 0, stream>>>(pool, cnt, b3, out);
}

// Round 5
// 342.998 us; speedup vs baseline: 5.5448x; 1.2685x over previous
//
#include <hip/hip_runtime.h>
#include <math.h>

#define NNODES 100000
#define NGRAPHS 64
#define NB 391  // ceil(100000 / 256) buckets of 256 nodes

// ================= bucketed CSR build =================
// bucket = dst >> 8; packed edge = (dst & 255) << 17 | src  (src < 2^17)

__global__ void bucket_count(const int* __restrict__ dst, int* __restrict__ bucketCnt, int E) {
    __shared__ int h[NB];
    for (int k = threadIdx.x; k < NB; k += 256) h[k] = 0;
    __syncthreads();
    int base = blockIdx.x * 2048 + threadIdx.x;
#pragma unroll
    for (int k = 0; k < 8; ++k) {
        int e = base + k * 256;
        if (e < E) atomicAdd(&h[dst[e] >> 8], 1);
    }
    __syncthreads();
    for (int k = threadIdx.x; k < NB; k += 256)
        if (h[k]) atomicAdd(&bucketCnt[k], h[k]);
}

__global__ void bucket_scan(const int* __restrict__ bucketCnt, int* __restrict__ bucketBase,
                            int* __restrict__ bucketCur, int E) {
    __shared__ int lds[512];
    int tid = threadIdx.x;
    lds[tid] = (tid < NB) ? bucketCnt[tid] : 0;
    __syncthreads();
    for (int off = 1; off < 512; off <<= 1) {
        int v = (tid >= off) ? lds[tid - off] : 0;
        __syncthreads();
        lds[tid] += v;
        __syncthreads();
    }
    int excl = (tid > 0) ? lds[tid - 1] : 0;
    if (tid < NB) {
        bucketBase[tid] = excl;
        bucketCur[tid] = excl;
    }
    if (tid == NB) bucketBase[NB] = excl;  // == E
}

__global__ void bucket_scatter(const int* __restrict__ src, const int* __restrict__ dst,
                               int* __restrict__ bucketCur, unsigned int* __restrict__ packed,
                               int E) {
    __shared__ int h[NB];
    __shared__ int cur[NB];
    for (int k = threadIdx.x; k < NB; k += 256) h[k] = 0;
    __syncthreads();
    int base = blockIdx.x * 2048 + threadIdx.x;
    int d[8], s[8], b[8];
#pragma unroll
    for (int k = 0; k < 8; ++k) {
        int e = base + k * 256;
        if (e < E) {
            d[k] = dst[e];
            s[k] = src[e];
            b[k] = d[k] >> 8;
            atomicAdd(&h[b[k]], 1);
        }
    }
    __syncthreads();
    for (int k = threadIdx.x; k < NB; k += 256) {
        int c = h[k];
        cur[k] = c ? atomicAdd(&bucketCur[k], c) : 0;
    }
    __syncthreads();
#pragma unroll
    for (int k = 0; k < 8; ++k) {
        int e = base + k * 256;
        if (e < E) {
            int pos = atomicAdd(&cur[b[k]], 1);
            packed[pos] = ((unsigned int)(d[k] & 255) << 17) | (unsigned int)s[k];
        }
    }
}

// one block per bucket: local histogram -> rowptr + dinv + sorted col
__global__ void bucket_build(const unsigned int* __restrict__ packed,
                             const int* __restrict__ bucketBase, int* __restrict__ rowptr,
                             int* __restrict__ col, float* __restrict__ dinv, int N_, int E) {
    __shared__ int cnt[256];
    __shared__ int bas[256];
    int tid = threadIdx.x;
    int b = blockIdx.x;
    int beg = bucketBase[b], end = bucketBase[b + 1];
    cnt[tid] = 0;
    __syncthreads();
    for (int k = beg + tid; k < end; k += 256) atomicAdd(&cnt[packed[k] >> 17], 1);
    __syncthreads();
    int myCnt = cnt[tid];
    bas[tid] = myCnt;
    __syncthreads();
    for (int off = 1; off < 256; off <<= 1) {
        int v = (tid >= off) ? bas[tid - off] : 0;
        __syncthreads();
        bas[tid] += v;
        __syncthreads();
    }
    int excl = beg + ((tid > 0) ? bas[tid - 1] : 0);
    int node = (b << 8) + tid;
    if (node <= N_) rowptr[node] = excl;   // includes rowptr[N] = E (bucket 390, tid 160)
    if (node < N_) dinv[node] = rsqrtf((float)myCnt + 1.0f);
    __syncthreads();
    bas[tid] = excl;  // becomes global cursor
    __syncthreads();
    for (int k = beg + tid; k < end; k += 256) {
        unsigned int p = packed[k];
        int pos = atomicAdd(&bas[p >> 17], 1);
        col[pos] = (int)(p & 0x1FFFFu);
    }
}

// ---------------- pos padding [N,3] -> float4 ----------------

__global__ void pad_pos(const float* __restrict__ pos, float4* __restrict__ p4, int n) {
    int i = blockIdx.x * blockDim.x + threadIdx.x;
    if (i < n) {
        float4 v;
        v.x = pos[i * 3 + 0];
        v.y = pos[i * 3 + 1];
        v.z = pos[i * 3 + 2];
        v.w = 0.0f;
        p4[i] = v;
    }
}

// ---------------- layer-1: aggregate pos (C=3 as float4), one thread per node ----------------

__global__ void gather_pos(const int* __restrict__ rowptr, const int* __restrict__ col,
                           const float4* __restrict__ p4, const float* __restrict__ dinv,
                           float4* __restrict__ outp, int n) {
    int i = blockIdx.x * blockDim.x + threadIdx.x;
    if (i >= n) return;
    float di = dinv[i];
    int beg = rowptr[i];
    int end = rowptr[i + 1];
    float4 sv = p4[i];
    float ax0 = sv.x * di, ay0 = sv.y * di, az0 = sv.z * di;
    float ax1 = 0, ay1 = 0, az1 = 0;
    float ax2 = 0, ay2 = 0, az2 = 0;
    float ax3 = 0, ay3 = 0, az3 = 0;
    int j = beg;
    for (; j + 4 <= end; j += 4) {
        int s0 = col[j], s1 = col[j + 1], s2 = col[j + 2], s3 = col[j + 3];
        float w0 = dinv[s0], w1 = dinv[s1], w2 = dinv[s2], w3 = dinv[s3];
        float4 v0 = p4[s0], v1 = p4[s1], v2 = p4[s2], v3 = p4[s3];
        ax0 += v0.x * w0; ay0 += v0.y * w0; az0 += v0.z * w0;
        ax1 += v1.x * w1; ay1 += v1.y * w1; az1 += v1.z * w1;
        ax2 += v2.x * w2; ay2 += v2.y * w2; az2 += v2.z * w2;
        ax3 += v3.x * w3; ay3 += v3.y * w3; az3 += v3.z * w3;
    }
    for (; j < end; ++j) {
        int s = col[j];
        float w = dinv[s];
        float4 v = p4[s];
        ax1 += v.x * w; ay1 += v.y * w; az1 += v.z * w;
    }
    float4 o;
    o.x = di * ((ax0 + ax1) + (ax2 + ax3));
    o.y = di * ((ay0 + ay1) + (ay2 + ay3));
    o.z = di * ((az0 + az1) + (az2 + az3));
    o.w = 0.0f;
    outp[i] = o;
}

// layer-1 matmul: out[i,f] = relu(aggP[i] . W1[:,f] + b1[f])
__global__ void mm1_fused(const float4* __restrict__ aggP, const float* __restrict__ W1,
                          const float* __restrict__ b1, float* __restrict__ out, int n) {
    int t = blockIdx.x * blockDim.x + threadIdx.x;
    if (t >= n * 64) return;
    int i = t >> 6;
    int f = t & 63;
    float4 x = aggP[i];
    float acc = b1[f] + x.x * W1[f] + x.y * W1[64 + f] + x.z * W1[128 + f];
    out[t] = fmaxf(acc, 0.0f);
}

// ---------------- LDS-tiled matmul: out[n,COUT] = x[n,64] @ W[64,COUT] ----------------

template <int F4, int TY>
__global__ void mm_tiled(const float4* __restrict__ x4, const float* __restrict__ W,
                         float4* __restrict__ out4, int n) {
    constexpr int ROWS = TY * 4;
    __shared__ float xs[ROWS][65];
    __shared__ float4 ws[64 * F4];
    const int tid = threadIdx.x;
    const int rowBase = blockIdx.x * ROWS;
    const int BT = F4 * TY;

    for (int idx = tid; idx < ROWS * 16; idx += BT) {
        int r = idx >> 4;
        int k4 = idx & 15;
        int gr = rowBase + r;
        float4 v = (gr < n) ? x4[(size_t)gr * 16 + k4] : make_float4(0, 0, 0, 0);
        xs[r][k4 * 4 + 0] = v.x;
        xs[r][k4 * 4 + 1] = v.y;
        xs[r][k4 * 4 + 2] = v.z;
        xs[r][k4 * 4 + 3] = v.w;
    }
    const float4* W4 = (const float4*)W;
    for (int idx = tid; idx < 64 * F4; idx += BT) ws[idx] = W4[idx];
    __syncthreads();

    const int f4 = tid % F4;
    const int r0 = (tid / F4) * 4;
    float4 a0 = make_float4(0, 0, 0, 0), a1 = a0, a2 = a0, a3 = a0;
#pragma unroll 4
    for (int k = 0; k < 64; ++k) {
        float4 wv = ws[k * F4 + f4];
        float xa = xs[r0 + 0][k];
        float xb = xs[r0 + 1][k];
        float xc = xs[r0 + 2][k];
        float xd = xs[r0 + 3][k];
        a0.x += wv.x * xa; a0.y += wv.y * xa; a0.z += wv.z * xa; a0.w += wv.w * xa;
        a1.x += wv.x * xb; a1.y += wv.y * xb; a1.z += wv.z * xb; a1.w += wv.w * xb;
        a2.x += wv.x * xc; a2.y += wv.y * xc; a2.z += wv.z * xc; a2.w += wv.w * xc;
        a3.x += wv.x * xd; a3.y += wv.y * xd; a3.z += wv.z * xd; a3.w += wv.w * xd;
    }
    if (rowBase + r0 + 0 < n) out4[(size_t)(rowBase + r0 + 0) * F4 + f4] = a0;
    if (rowBase + r0 + 1 < n) out4[(size_t)(rowBase + r0 + 1) * F4 + f4] = a1;
    if (rowBase + r0 + 2 < n) out4[(size_t)(rowBase + r0 + 2) * F4 + f4] = a2;
    if (rowBase + r0 + 3 < n) out4[(size_t)(rowBase + r0 + 3) * F4 + f4] = a3;
}

// ---------------- CSR gather aggregation, float4 channels + 4-way edge ILP ----------------

template <int C4, bool RELU, bool BIAS>
__global__ void gather_agg4(const int* __restrict__ rowptr, const int* __restrict__ col,
                            const float4* __restrict__ h, const float* __restrict__ dinv,
                            const float* __restrict__ bias, float4* __restrict__ out, int n) {
    int t = blockIdx.x * blockDim.x + threadIdx.x;
    if (t >= n * C4) return;
    int i = t / C4;
    int c4 = t - i * C4;
    float di = dinv[i];
    int beg = rowptr[i];
    int end = rowptr[i + 1];
    float4 hs = h[t];
    float4 a0, a1, a2, a3;
    a0.x = hs.x * di; a0.y = hs.y * di; a0.z = hs.z * di; a0.w = hs.w * di;
    a1 = make_float4(0, 0, 0, 0); a2 = a1; a3 = a1;
    int j = beg;
    for (; j + 4 <= end; j += 4) {
        int s0 = col[j], s1 = col[j + 1], s2 = col[j + 2], s3 = col[j + 3];
        float w0 = dinv[s0], w1 = dinv[s1], w2 = dinv[s2], w3 = dinv[s3];
        float4 v0 = h[(size_t)s0 * C4 + c4];
        float4 v1 = h[(size_t)s1 * C4 + c4];
        float4 v2 = h[(size_t)s2 * C4 + c4];
        float4 v3 = h[(size_t)s3 * C4 + c4];
        a0.x += v0.x * w0; a0.y += v0.y * w0; a0.z += v0.z * w0; a0.w += v0.w * w0;
        a1.x += v1.x * w1; a1.y += v1.y * w1; a1.z += v1.z * w1; a1.w += v1.w * w1;
        a2.x += v2.x * w2; a2.y += v2.y * w2; a2.z += v2.z * w2; a2.w += v2.w * w2;
        a3.x += v3.x * w3; a3.y += v3.y * w3; a3.z += v3.z * w3; a3.w += v3.w * w3;
    }
    for (; j < end; ++j) {
        int s = col[j];
        float w = dinv[s];
        float4 v = h[(size_t)s * C4 + c4];
        a1.x += v.x * w; a1.y += v.y * w; a1.z += v.z * w; a1.w += v.w * w;
    }
    float4 acc;
    acc.x = di * ((a0.x + a1.x) + (a2.x + a3.x));
    acc.y = di * ((a0.y + a1.y) + (a2.y + a3.y));
    acc.z = di * ((a0.z + a1.z) + (a2.z + a3.z));
    acc.w = di * ((a0.w + a1.w) + (a2.w + a3.w));
    if (BIAS) {
        float4 bv = ((const float4*)bias)[c4];
        acc.x += bv.x; acc.y += bv.y; acc.z += bv.z; acc.w += bv.w;
    }
    if (RELU) {
        acc.x = fmaxf(acc.x, 0.0f); acc.y = fmaxf(acc.y, 0.0f);
        acc.z = fmaxf(acc.z, 0.0f); acc.w = fmaxf(acc.w, 0.0f);
    }
    out[t] = acc;
}

// ---------------- pooling: LDS two-stage ----------------

__global__ void pool_reduce(const float* __restrict__ y, const int* __restrict__ batch,
                            float* __restrict__ sums, float* __restrict__ cnt, int n) {
    __shared__ float ls[NGRAPHS * 24];
    __shared__ float lc[NGRAPHS];
    for (int k = threadIdx.x; k < NGRAPHS * 24; k += blockDim.x) ls[k] = 0.0f;
    for (int k = threadIdx.x; k < NGRAPHS; k += blockDim.x) lc[k] = 0.0f;
    __syncthreads();
    int total = n * 24;
    int stride = gridDim.x * blockDim.x;
    for (int t = blockIdx.x * blockDim.x + threadIdx.x; t < total; t += stride) {
        int i = t / 24;
        int c = t - i * 24;
        atomicAdd(&ls[batch[i] * 24 + c], y[t]);
    }
    for (int i = blockIdx.x * blockDim.x + threadIdx.x; i < n; i += stride) {
        atomicAdd(&lc[batch[i]], 1.0f);
    }
    __syncthreads();
    for (int k = threadIdx.x; k < NGRAPHS * 24; k += blockDim.x)
        if (ls[k] != 0.0f) atomicAdd(&sums[k], ls[k]);
    for (int k = threadIdx.x; k < NGRAPHS; k += blockDim.x)
        if (lc[k] != 0.0f) atomicAdd(&cnt[k], lc[k]);
}

__global__ void pool_finish(const float* __restrict__ sums, const float* __restrict__ cnt,
                            const float* __restrict__ b3, float* __restrict__ out) {
    int t = blockIdx.x * blockDim.x + threadIdx.x;
    if (t >= NGRAPHS * 24) return;
    int g = t / 24;
    int c = t - g * 24;
    float m = sums[t] / fmaxf(cnt[g], 1.0f) + b3[c];
    out[t] = tanhf(m);
}

// ---------------- launch ----------------

static inline int gridFor(long long total, int block) {
    return (int)((total + block - 1) / block);
}

extern "C" void kernel_launch(void* const* d_in, const int* in_sizes, int n_in,
                              void* d_out, int out_size, void* d_ws, size_t ws_size,
                              hipStream_t stream) {
    const float* pos   = (const float*)d_in[0];
    const int*   ei    = (const int*)d_in[1];
    const int*   batch = (const int*)d_in[2];
    const float* W1    = (const float*)d_in[3];
    const float* b1    = (const float*)d_in[4];
    const float* W2    = (const float*)d_in[5];
    const float* b2    = (const float*)d_in[6];
    const float* W3    = (const float*)d_in[7];
    const float* b3    = (const float*)d_in[8];
    float*       out   = (float*)d_out;

    const int N = NNODES;
    const int E = in_sizes[1] / 2;
    const int* src = ei;
    const int* dst = ei + E;

    // ---- workspace layout (16B-aligned chunks first) ----
    char* p = (char*)d_ws;
    float4* pos4   = (float4*)p;        p += (size_t)N * sizeof(float4);
    float4* aggP   = (float4*)p;        p += (size_t)N * sizeof(float4);
    float*  bufH   = (float*)p;         p += (size_t)N * 64 * sizeof(float);
    float*  bufA   = (float*)p;         p += (size_t)N * 64 * sizeof(float);
    float*  dinv   = (float*)p;         p += (size_t)N * sizeof(float);
    float*  pool   = (float*)p;         p += (size_t)NGRAPHS * 24 * sizeof(float);
    float*  cnt    = (float*)p;         p += (size_t)NGRAPHS * sizeof(float);
    int*    rowptr = (int*)p;           p += (size_t)(N + 1) * sizeof(int);
    int*    bCnt   = (int*)p;           p += (NB + 1) * sizeof(int);
    int*    bBase  = (int*)p;           p += (NB + 1) * sizeof(int);
    int*    bCur   = (int*)p;           p += (NB + 1) * sizeof(int);
    unsigned int* packed = (unsigned int*)p;  p += (size_t)E * sizeof(unsigned int);
    int*    col    = (int*)p;           p += (size_t)E * sizeof(int);

    const int B = 256;
    const int edgeBlocks = gridFor(E, 2048);

    // ---- CSR build: bucketed counting sort (also emits rowptr + dinv) ----
    hipMemsetAsync(bCnt, 0, (NB + 1) * sizeof(int), stream);
    bucket_count<<<edgeBlocks, 256, 0, stream>>>(dst, bCnt, E);
    bucket_scan<<<1, 512, 0, stream>>>(bCnt, bBase, bCur, E);
    bucket_scatter<<<edgeBlocks, 256, 0, stream>>>(src, dst, bCur, packed, E);
    bucket_build<<<NB, 256, 0, stream>>>(packed, bBase, rowptr, col, dinv, N, E);

    // ---- layer 1: agg(pos) @ W1 + b1, relu  (aggregation commutes with matmul) ----
    pad_pos<<<gridFor(N, B), B, 0, stream>>>(pos, pos4, N);
    gather_pos<<<gridFor(N, B), B, 0, stream>>>(rowptr, col, pos4, dinv, aggP, N);
    mm1_fused<<<gridFor((long long)N * 64, B), B, 0, stream>>>(aggP, W1, b1, bufA, N);

    // ---- layer 2: h2 = relu(agg(h1 @ W2) + b2) ----
    mm_tiled<16, 16><<<gridFor(N, 64), 256, 0, stream>>>(
        (const float4*)bufA, W2, (float4*)bufH, N);
    gather_agg4<16, true, true><<<gridFor((long long)N * 16, B), B, 0, stream>>>(
        rowptr, col, (const float4*)bufH, dinv, b2, (float4*)bufA, N);

    // ---- layer 3: y = agg(h2 @ W3)  (b3 folded into pool_finish) ----
    mm_tiled<6, 32><<<gridFor(N, 128), 192, 0, stream>>>(
        (const float4*)bufA, W3, (float4*)bufH, N);
    gather_agg4<6, false, false><<<gridFor((long long)N * 6, B), B, 0, stream>>>(
        rowptr, col, (const float4*)bufH, dinv, (const float*)nullptr, (float4*)bufA, N);

    // ---- pool ----
    hipMemsetAsync(pool, 0, (size_t)(NGRAPHS * 24 + NGRAPHS) * sizeof(float), stream);
    pool_reduce<<<256, 256, 0, stream>>>(bufA, batch, pool, cnt, N);
    pool_finish<<<gridFor(NGRAPHS * 24, B), B, 0, stream>>>(pool, cnt, b3, out);
}

// Round 6
// 317.691 us; speedup vs baseline: 5.9864x; 1.0797x over previous
//
#include <hip/hip_runtime.h>
#include <math.h>

#define NNODES 100000
#define NGRAPHS 64
#define NB 391  // ceil(100000 / 256) buckets of 256 nodes

// ---------- bf16 helpers (RNE pack, shift unpack) ----------

__device__ __forceinline__ unsigned int f2bf(float x) {
    union { float f; unsigned int u; } v;
    v.f = x;
    unsigned int r = v.u + 0x7FFFu + ((v.u >> 16) & 1u);
    return r >> 16;
}
__device__ __forceinline__ unsigned int pack2bf(float lo, float hi) {
    return f2bf(lo) | (f2bf(hi) << 16);
}
__device__ __forceinline__ float bflo(unsigned int u) {
    union { unsigned int u; float f; } v;
    v.u = u << 16;
    return v.f;
}
__device__ __forceinline__ float bfhi(unsigned int u) {
    union { unsigned int u; float f; } v;
    v.u = u & 0xFFFF0000u;
    return v.f;
}

// ================= bucketed CSR build =================
// bucket = dst >> 8; packed edge = (dst & 255) << 17 | src  (src < 2^17)

__global__ void bucket_count(const int* __restrict__ dst, int* __restrict__ bucketCnt, int E) {
    __shared__ int h[NB];
    for (int k = threadIdx.x; k < NB; k += 256) h[k] = 0;
    __syncthreads();
    int base = blockIdx.x * 2048 + threadIdx.x;
#pragma unroll
    for (int k = 0; k < 8; ++k) {
        int e = base + k * 256;
        if (e < E) atomicAdd(&h[dst[e] >> 8], 1);
    }
    __syncthreads();
    for (int k = threadIdx.x; k < NB; k += 256)
        if (h[k]) atomicAdd(&bucketCnt[k], h[k]);
}

__global__ void bucket_scan(const int* __restrict__ bucketCnt, int* __restrict__ bucketBase,
                            int* __restrict__ bucketCur, int E) {
    __shared__ int lds[512];
    int tid = threadIdx.x;
    lds[tid] = (tid < NB) ? bucketCnt[tid] : 0;
    __syncthreads();
    for (int off = 1; off < 512; off <<= 1) {
        int v = (tid >= off) ? lds[tid - off] : 0;
        __syncthreads();
        lds[tid] += v;
        __syncthreads();
    }
    int excl = (tid > 0) ? lds[tid - 1] : 0;
    if (tid < NB) {
        bucketBase[tid] = excl;
        bucketCur[tid] = excl;
    }
    if (tid == NB) bucketBase[NB] = excl;  // == E
}

__global__ void bucket_scatter(const int* __restrict__ src, const int* __restrict__ dst,
                               int* __restrict__ bucketCur, unsigned int* __restrict__ packed,
                               int E) {
    __shared__ int h[NB];
    __shared__ int cur[NB];
    for (int k = threadIdx.x; k < NB; k += 256) h[k] = 0;
    __syncthreads();
    int base = blockIdx.x * 2048 + threadIdx.x;
    int d[8], s[8], b[8];
#pragma unroll
    for (int k = 0; k < 8; ++k) {
        int e = base + k * 256;
        if (e < E) {
            d[k] = dst[e];
            s[k] = src[e];
            b[k] = d[k] >> 8;
            atomicAdd(&h[b[k]], 1);
        }
    }
    __syncthreads();
    for (int k = threadIdx.x; k < NB; k += 256) {
        int c = h[k];
        cur[k] = c ? atomicAdd(&bucketCur[k], c) : 0;
    }
    __syncthreads();
#pragma unroll
    for (int k = 0; k < 8; ++k) {
        int e = base + k * 256;
        if (e < E) {
            int pos = atomicAdd(&cur[b[k]], 1);
            packed[pos] = ((unsigned int)(d[k] & 255) << 17) | (unsigned int)s[k];
        }
    }
}

// one block per bucket: local histogram -> rowptr + dinv + sorted col
__global__ void bucket_build(const unsigned int* __restrict__ packed,
                             const int* __restrict__ bucketBase, int* __restrict__ rowptr,
                             int* __restrict__ col, float* __restrict__ dinv, int N_, int E) {
    __shared__ int cnt[256];
    __shared__ int bas[256];
    int tid = threadIdx.x;
    int b = blockIdx.x;
    int beg = bucketBase[b], end = bucketBase[b + 1];
    cnt[tid] = 0;
    __syncthreads();
    for (int k = beg + tid; k < end; k += 256) atomicAdd(&cnt[packed[k] >> 17], 1);
    __syncthreads();
    int myCnt = cnt[tid];
    bas[tid] = myCnt;
    __syncthreads();
    for (int off = 1; off < 256; off <<= 1) {
        int v = (tid >= off) ? bas[tid - off] : 0;
        __syncthreads();
        bas[tid] += v;
        __syncthreads();
    }
    int excl = beg + ((tid > 0) ? bas[tid - 1] : 0);
    int node = (b << 8) + tid;
    if (node <= N_) rowptr[node] = excl;
    if (node < N_) dinv[node] = rsqrtf((float)myCnt + 1.0f);
    __syncthreads();
    bas[tid] = excl;
    __syncthreads();
    for (int k = beg + tid; k < end; k += 256) {
        unsigned int p = packed[k];
        int pos = atomicAdd(&bas[p >> 17], 1);
        col[pos] = (int)(p & 0x1FFFFu);
    }
}

// ---------------- pos padding [N,3] -> float4 ----------------

__global__ void pad_pos(const float* __restrict__ pos, float4* __restrict__ p4, int n) {
    int i = blockIdx.x * blockDim.x + threadIdx.x;
    if (i < n) {
        float4 v;
        v.x = pos[i * 3 + 0];
        v.y = pos[i * 3 + 1];
        v.z = pos[i * 3 + 2];
        v.w = 0.0f;
        p4[i] = v;
    }
}

// ---------------- layer-1: aggregate pos (C=3 as float4), fp32 exact ----------------

__global__ void gather_pos(const int* __restrict__ rowptr, const int* __restrict__ col,
                           const float4* __restrict__ p4, const float* __restrict__ dinv,
                           float4* __restrict__ outp, int n) {
    int i = blockIdx.x * blockDim.x + threadIdx.x;
    if (i >= n) return;
    float di = dinv[i];
    int beg = rowptr[i];
    int end = rowptr[i + 1];
    float4 sv = p4[i];
    float ax0 = sv.x * di, ay0 = sv.y * di, az0 = sv.z * di;
    float ax1 = 0, ay1 = 0, az1 = 0;
    float ax2 = 0, ay2 = 0, az2 = 0;
    float ax3 = 0, ay3 = 0, az3 = 0;
    int j = beg;
    for (; j + 4 <= end; j += 4) {
        int s0 = col[j], s1 = col[j + 1], s2 = col[j + 2], s3 = col[j + 3];
        float w0 = dinv[s0], w1 = dinv[s1], w2 = dinv[s2], w3 = dinv[s3];
        float4 v0 = p4[s0], v1 = p4[s1], v2 = p4[s2], v3 = p4[s3];
        ax0 += v0.x * w0; ay0 += v0.y * w0; az0 += v0.z * w0;
        ax1 += v1.x * w1; ay1 += v1.y * w1; az1 += v1.z * w1;
        ax2 += v2.x * w2; ay2 += v2.y * w2; az2 += v2.z * w2;
        ax3 += v3.x * w3; ay3 += v3.y * w3; az3 += v3.z * w3;
    }
    for (; j < end; ++j) {
        int s = col[j];
        float w = dinv[s];
        float4 v = p4[s];
        ax1 += v.x * w; ay1 += v.y * w; az1 += v.z * w;
    }
    float4 o;
    o.x = di * ((ax0 + ax1) + (ax2 + ax3));
    o.y = di * ((ay0 + ay1) + (ay2 + ay3));
    o.z = di * ((az0 + az1) + (az2 + az3));
    o.w = 0.0f;
    outp[i] = o;
}

// layer-1 matmul: out[i,f] = relu(aggP[i] . W1[:,f] + b1[f])  (fp32 out, feeds mm_tiled)
__global__ void mm1_fused(const float4* __restrict__ aggP, const float* __restrict__ W1,
                          const float* __restrict__ b1, float* __restrict__ out, int n) {
    int t = blockIdx.x * blockDim.x + threadIdx.x;
    if (t >= n * 64) return;
    int i = t >> 6;
    int f = t & 63;
    float4 x = aggP[i];
    float acc = b1[f] + x.x * W1[f] + x.y * W1[64 + f] + x.z * W1[128 + f];
    out[t] = fmaxf(acc, 0.0f);
}

// ---------------- LDS-tiled matmul -> packed bf16 output ----------------
// out[n,COUT] = x[n,64] @ W[64,COUT], stored as bf16 (uint2 = 4 ch per thread-col-group)

template <int F4, int TY>
__global__ void mm_tiled_b16(const float4* __restrict__ x4, const float* __restrict__ W,
                             uint2* __restrict__ outb, int n) {
    constexpr int ROWS = TY * 4;
    __shared__ float xs[ROWS][65];
    __shared__ float4 ws[64 * F4];
    const int tid = threadIdx.x;
    const int rowBase = blockIdx.x * ROWS;
    const int BT = F4 * TY;

    for (int idx = tid; idx < ROWS * 16; idx += BT) {
        int r = idx >> 4;
        int k4 = idx & 15;
        int gr = rowBase + r;
        float4 v = (gr < n) ? x4[(size_t)gr * 16 + k4] : make_float4(0, 0, 0, 0);
        xs[r][k4 * 4 + 0] = v.x;
        xs[r][k4 * 4 + 1] = v.y;
        xs[r][k4 * 4 + 2] = v.z;
        xs[r][k4 * 4 + 3] = v.w;
    }
    const float4* W4 = (const float4*)W;
    for (int idx = tid; idx < 64 * F4; idx += BT) ws[idx] = W4[idx];
    __syncthreads();

    const int f4 = tid % F4;
    const int r0 = (tid / F4) * 4;
    float4 a0 = make_float4(0, 0, 0, 0), a1 = a0, a2 = a0, a3 = a0;
#pragma unroll 4
    for (int k = 0; k < 64; ++k) {
        float4 wv = ws[k * F4 + f4];
        float xa = xs[r0 + 0][k];
        float xb = xs[r0 + 1][k];
        float xc = xs[r0 + 2][k];
        float xd = xs[r0 + 3][k];
        a0.x += wv.x * xa; a0.y += wv.y * xa; a0.z += wv.z * xa; a0.w += wv.w * xa;
        a1.x += wv.x * xb; a1.y += wv.y * xb; a1.z += wv.z * xb; a1.w += wv.w * xb;
        a2.x += wv.x * xc; a2.y += wv.y * xc; a2.z += wv.z * xc; a2.w += wv.w * xc;
        a3.x += wv.x * xd; a3.y += wv.y * xd; a3.z += wv.z * xd; a3.w += wv.w * xd;
    }
    // row stride = F4 uint2
    if (rowBase + r0 + 0 < n)
        outb[(size_t)(rowBase + r0 + 0) * F4 + f4] = make_uint2(pack2bf(a0.x, a0.y), pack2bf(a0.z, a0.w));
    if (rowBase + r0 + 1 < n)
        outb[(size_t)(rowBase + r0 + 1) * F4 + f4] = make_uint2(pack2bf(a1.x, a1.y), pack2bf(a1.z, a1.w));
    if (rowBase + r0 + 2 < n)
        outb[(size_t)(rowBase + r0 + 2) * F4 + f4] = make_uint2(pack2bf(a2.x, a2.y), pack2bf(a2.z, a2.w));
    if (rowBase + r0 + 3 < n)
        outb[(size_t)(rowBase + r0 + 3) * F4 + f4] = make_uint2(pack2bf(a3.x, a3.y), pack2bf(a3.z, a3.w));
}

// ---------------- CSR gather on bf16 features: 8 ch/thread, 8-way edge ILP ----------------
// h row i = C8 uint4 (each uint4 = 8 bf16). out fp32 row = C8*8 floats.

template <int C8, bool RELU, bool BIAS>
__global__ void gather_b16(const int* __restrict__ rowptr, const int* __restrict__ col,
                           const uint4* __restrict__ h, const float* __restrict__ dinv,
                           const float* __restrict__ bias, float4* __restrict__ out, int n) {
    int t = blockIdx.x * blockDim.x + threadIdx.x;
    if (t >= n * C8) return;
    int i = t / C8;
    int c8 = t - i * C8;
    float di = dinv[i];
    int beg = rowptr[i];
    int end = rowptr[i + 1];

    float acc[8];
    {
        uint4 sv = h[(size_t)i * C8 + c8];
        acc[0] = bflo(sv.x) * di; acc[1] = bfhi(sv.x) * di;
        acc[2] = bflo(sv.y) * di; acc[3] = bfhi(sv.y) * di;
        acc[4] = bflo(sv.z) * di; acc[5] = bfhi(sv.z) * di;
        acc[6] = bflo(sv.w) * di; acc[7] = bfhi(sv.w) * di;
    }
    int j = beg;
    for (; j + 8 <= end; j += 8) {
        int s[8];
        float w[8];
        uint4 v[8];
#pragma unroll
        for (int k = 0; k < 8; ++k) s[k] = col[j + k];
#pragma unroll
        for (int k = 0; k < 8; ++k) {
            v[k] = h[(size_t)s[k] * C8 + c8];
            w[k] = dinv[s[k]];
        }
#pragma unroll
        for (int k = 0; k < 8; ++k) {
            acc[0] += bflo(v[k].x) * w[k]; acc[1] += bfhi(v[k].x) * w[k];
            acc[2] += bflo(v[k].y) * w[k]; acc[3] += bfhi(v[k].y) * w[k];
            acc[4] += bflo(v[k].z) * w[k]; acc[5] += bfhi(v[k].z) * w[k];
            acc[6] += bflo(v[k].w) * w[k]; acc[7] += bfhi(v[k].w) * w[k];
        }
    }
    for (; j + 4 <= end; j += 4) {
        int s[4];
        float w[4];
        uint4 v[4];
#pragma unroll
        for (int k = 0; k < 4; ++k) s[k] = col[j + k];
#pragma unroll
        for (int k = 0; k < 4; ++k) {
            v[k] = h[(size_t)s[k] * C8 + c8];
            w[k] = dinv[s[k]];
        }
#pragma unroll
        for (int k = 0; k < 4; ++k) {
            acc[0] += bflo(v[k].x) * w[k]; acc[1] += bfhi(v[k].x) * w[k];
            acc[2] += bflo(v[k].y) * w[k]; acc[3] += bfhi(v[k].y) * w[k];
            acc[4] += bflo(v[k].z) * w[k]; acc[5] += bfhi(v[k].z) * w[k];
            acc[6] += bflo(v[k].w) * w[k]; acc[7] += bfhi(v[k].w) * w[k];
        }
    }
    for (; j < end; ++j) {
        int s = col[j];
        float w = dinv[s];
        uint4 v = h[(size_t)s * C8 + c8];
        acc[0] += bflo(v.x) * w; acc[1] += bfhi(v.x) * w;
        acc[2] += bflo(v.y) * w; acc[3] += bfhi(v.y) * w;
        acc[4] += bflo(v.z) * w; acc[5] += bfhi(v.z) * w;
        acc[6] += bflo(v.w) * w; acc[7] += bfhi(v.w) * w;
    }
#pragma unroll
    for (int k = 0; k < 8; ++k) acc[k] *= di;
    if (BIAS) {
        const float* bv = bias + c8 * 8;
#pragma unroll
        for (int k = 0; k < 8; ++k) acc[k] += bv[k];
    }
    if (RELU) {
#pragma unroll
        for (int k = 0; k < 8; ++k) acc[k] = fmaxf(acc[k], 0.0f);
    }
    float4 o0 = make_float4(acc[0], acc[1], acc[2], acc[3]);
    float4 o1 = make_float4(acc[4], acc[5], acc[6], acc[7]);
    out[(size_t)t * 2 + 0] = o0;
    out[(size_t)t * 2 + 1] = o1;
}

// ---------------- pooling: LDS two-stage ----------------

__global__ void pool_reduce(const float* __restrict__ y, const int* __restrict__ batch,
                            float* __restrict__ sums, float* __restrict__ cnt, int n) {
    __shared__ float ls[NGRAPHS * 24];
    __shared__ float lc[NGRAPHS];
    for (int k = threadIdx.x; k < NGRAPHS * 24; k += blockDim.x) ls[k] = 0.0f;
    for (int k = threadIdx.x; k < NGRAPHS; k += blockDim.x) lc[k] = 0.0f;
    __syncthreads();
    int total = n * 24;
    int stride = gridDim.x * blockDim.x;
    for (int t = blockIdx.x * blockDim.x + threadIdx.x; t < total; t += stride) {
        int i = t / 24;
        int c = t - i * 24;
        atomicAdd(&ls[batch[i] * 24 + c], y[t]);
    }
    for (int i = blockIdx.x * blockDim.x + threadIdx.x; i < n; i += stride) {
        atomicAdd(&lc[batch[i]], 1.0f);
    }
    __syncthreads();
    for (int k = threadIdx.x; k < NGRAPHS * 24; k += blockDim.x)
        if (ls[k] != 0.0f) atomicAdd(&sums[k], ls[k]);
    for (int k = threadIdx.x; k < NGRAPHS; k += blockDim.x)
        if (lc[k] != 0.0f) atomicAdd(&cnt[k], lc[k]);
}

__global__ void pool_finish(const float* __restrict__ sums, const float* __restrict__ cnt,
                            const float* __restrict__ b3, float* __restrict__ out) {
    int t = blockIdx.x * blockDim.x + threadIdx.x;
    if (t >= NGRAPHS * 24) return;
    int g = t / 24;
    int c = t - g * 24;
    float m = sums[t] / fmaxf(cnt[g], 1.0f) + b3[c];
    out[t] = tanhf(m);
}

// ---------------- launch ----------------

static inline int gridFor(long long total, int block) {
    return (int)((total + block - 1) / block);
}

extern "C" void kernel_launch(void* const* d_in, const int* in_sizes, int n_in,
                              void* d_out, int out_size, void* d_ws, size_t ws_size,
                              hipStream_t stream) {
    const float* pos   = (const float*)d_in[0];
    const int*   ei    = (const int*)d_in[1];
    const int*   batch = (const int*)d_in[2];
    const float* W1    = (const float*)d_in[3];
    const float* b1    = (const float*)d_in[4];
    const float* W2    = (const float*)d_in[5];
    const float* b2    = (const float*)d_in[6];
    const float* W3    = (const float*)d_in[7];
    const float* b3    = (const float*)d_in[8];
    float*       out   = (float*)d_out;

    const int N = NNODES;
    const int E = in_sizes[1] / 2;
    const int* src = ei;
    const int* dst = ei + E;

    // ---- workspace layout (16B-aligned chunks first) ----
    char* p = (char*)d_ws;
    float4* pos4   = (float4*)p;        p += (size_t)N * sizeof(float4);
    float4* aggP   = (float4*)p;        p += (size_t)N * sizeof(float4);
    float*  bufA   = (float*)p;         p += (size_t)N * 64 * sizeof(float);    // fp32 features
    unsigned int* bufB = (unsigned int*)p;  p += (size_t)N * 32 * sizeof(unsigned int);  // bf16 features (64ch)
    float*  bufY   = (float*)p;         p += (size_t)N * 24 * sizeof(float);    // final y
    float*  dinv   = (float*)p;         p += (size_t)N * sizeof(float);
    float*  pool   = (float*)p;         p += (size_t)NGRAPHS * 24 * sizeof(float);
    float*  cnt    = (float*)p;         p += (size_t)NGRAPHS * sizeof(float);
    int*    rowptr = (int*)p;           p += (size_t)(N + 1) * sizeof(int);
    int*    bCnt   = (int*)p;           p += (NB + 1) * sizeof(int);
    int*    bBase  = (int*)p;           p += (NB + 1) * sizeof(int);
    int*    bCur   = (int*)p;           p += (NB + 1) * sizeof(int);
    unsigned int* packed = (unsigned int*)p;  p += (size_t)E * sizeof(unsigned int);
    int*    col    = (int*)p;           p += (size_t)E * sizeof(int);

    const int B = 256;
    const int edgeBlocks = gridFor(E, 2048);

    // ---- CSR build: bucketed counting sort (emits rowptr + dinv too) ----
    hipMemsetAsync(bCnt, 0, (NB + 1) * sizeof(int), stream);
    bucket_count<<<edgeBlocks, 256, 0, stream>>>(dst, bCnt, E);
    bucket_scan<<<1, 512, 0, stream>>>(bCnt, bBase, bCur, E);
    bucket_scatter<<<edgeBlocks, 256, 0, stream>>>(src, dst, bCur, packed, E);
    bucket_build<<<NB, 256, 0, stream>>>(packed, bBase, rowptr, col, dinv, N, E);

    // ---- layer 1: agg(pos) @ W1 + b1, relu  (fp32 exact path) ----
    pad_pos<<<gridFor(N, B), B, 0, stream>>>(pos, pos4, N);
    gather_pos<<<gridFor(N, B), B, 0, stream>>>(rowptr, col, pos4, dinv, aggP, N);
    mm1_fused<<<gridFor((long long)N * 64, B), B, 0, stream>>>(aggP, W1, b1, bufA, N);

    // ---- layer 2: h2 = relu(agg(h1 @ W2) + b2), bf16 gather features ----
    mm_tiled_b16<16, 16><<<gridFor(N, 64), 256, 0, stream>>>(
        (const float4*)bufA, W2, (uint2*)bufB, N);
    gather_b16<8, true, true><<<gridFor((long long)N * 8, B), B, 0, stream>>>(
        rowptr, col, (const uint4*)bufB, dinv, b2, (float4*)bufA, N);

    // ---- layer 3: y = agg(h2 @ W3), bf16 gather features (b3 folded into pool_finish) ----
    mm_tiled_b16<6, 32><<<gridFor(N, 128), 192, 0, stream>>>(
        (const float4*)bufA, W3, (uint2*)bufB, N);
    gather_b16<3, false, false><<<gridFor((long long)N * 3, B), B, 0, stream>>>(
        rowptr, col, (const uint4*)bufB, dinv, (const float*)nullptr, (float4*)bufY, N);

    // ---- pool ----
    hipMemsetAsync(pool, 0, (size_t)(NGRAPHS * 24 + NGRAPHS) * sizeof(float), stream);
    pool_reduce<<<256, 256, 0, stream>>>(bufY, batch, pool, cnt, N);
    pool_finish<<<gridFor(NGRAPHS * 24, B), B, 0, stream>>>(pool, cnt, b3, out);
}